// Round 6
// baseline (314.270 us; speedup 1.0000x reference)
//
#include <hip/hip_runtime.h>
#include <hip/hip_bf16.h>

#define ROWS 16384
#define C_   256
#define H1_  256
#define H2_  64
#define EPSN 1e-5f

typedef __bf16 bf16x8 __attribute__((ext_vector_type(8)));
typedef __bf16 bf16x4 __attribute__((ext_vector_type(4)));
typedef __bf16 bf16x2 __attribute__((ext_vector_type(2)));
typedef float  f32x4  __attribute__((ext_vector_type(4)));
typedef float  f32x2  __attribute__((ext_vector_type(2)));

__device__ __forceinline__ bf16x2 cvt2(float a, float b) {
#if __has_builtin(__builtin_amdgcn_cvt_pk_bf16_f32)
    return __builtin_bit_cast(bf16x2, __builtin_amdgcn_cvt_pk_bf16_f32(a, b));
#else
    bf16x2 r; r[0] = (__bf16)a; r[1] = (__bf16)b; return r;
#endif
}

// ---------------- K0: pack W1/W2/W3 into MFMA fragment order, zero partial buffers --
// Frag layout (16x16x32 bf16, A/B index-symmetric): lane l supplies [k=(l>>4)*8+j][idx=l&15].
__global__ __launch_bounds__(256) void k0_pack(const float* __restrict__ W1,
                                               const float* __restrict__ W2,
                                               const float* __restrict__ W3,
                                               __bf16* __restrict__ W1p,
                                               __bf16* __restrict__ W2p,
                                               __bf16* __restrict__ W3p,
                                               float* __restrict__ zero_base) {
    int idx = blockIdx.x * 256 + threadIdx.x;   // 0 .. 81919
    if (idx < 65536) {
        int j = idx & 7, l = (idx >> 3) & 63, rest = idx >> 9;
        int ks = rest & 7, CT = rest >> 3;
        int k = ks * 32 + ((l >> 4) << 3) + j;
        int c = CT * 16 + (l & 15);
        W1p[idx] = (__bf16)W1[k * H1_ + c];
    } else {
        int i2 = idx - 65536;
        int j = i2 & 7, l = (i2 >> 3) & 63, rest = i2 >> 9;
        int ks = rest & 7, CK = rest >> 3;
        int k = ks * 32 + ((l >> 4) << 3) + j;
        int c2 = CK * 16 + (l & 15);
        W2p[i2] = (__bf16)W2[k * H2_ + c2];
    }
    if (idx < 1024) {
        int j = idx & 7, l = (idx >> 3) & 63, ks = idx >> 9;
        int k = ks * 32 + ((l >> 4) << 3) + j;
        int c = l & 15;
        W3p[idx] = (c < 3) ? (__bf16)W3[k * 3 + c] : (__bf16)0.f;
    }
    if (idx < 24576) zero_base[idx] = 0.0f;     // p1s,p1q,p2s,p2q contiguous
}

// ---------------- K1a: tokpart = tokens @ W1[:C] ; per-channel stats ; coarse -------
__global__ __launch_bounds__(256) void k1a(const float* __restrict__ tokens,
                                           const __bf16* __restrict__ W1p,
                                           const float* __restrict__ Wc,
                                           const float* __restrict__ bc,
                                           float* __restrict__ tokpart,
                                           float* __restrict__ coarse,
                                           float* __restrict__ p1s,
                                           float* __restrict__ p1q) {
    __shared__ __align__(16) __bf16 Al[16 * 264];
    int t = threadIdx.x, w = t >> 6, l = t & 63;
    int quad = l >> 4, col = l & 15;
    int rowbase = (blockIdx.x >> 1) * 16;
    int colhalf = blockIdx.x & 1;
    int slot = blockIdx.x & 31;

    bf16x8 bfr[16];
#pragma unroll
    for (int ctl = 0; ctl < 2; ++ctl)
#pragma unroll
        for (int ks = 0; ks < 8; ++ks) {
            int CT = colhalf * 8 + w * 2 + ctl;
            bfr[ctl * 8 + ks] = *(const bf16x8*)(W1p + (((CT * 8 + ks) * 64 + l) * 8));
        }
    {
        int r = t >> 4, cb = (t & 15) * 16;
        const float* src = tokens + (size_t)(rowbase + r) * C_ + cb;
        f32x4 t0 = *(const f32x4*)(src);
        f32x4 t1 = *(const f32x4*)(src + 4);
        f32x4 t2 = *(const f32x4*)(src + 8);
        f32x4 t3 = *(const f32x4*)(src + 12);
        bf16x8 v0, v1;
        bf16x2* p0 = (bf16x2*)&v0; bf16x2* p1 = (bf16x2*)&v1;
        p0[0] = cvt2(t0[0], t0[1]); p0[1] = cvt2(t0[2], t0[3]);
        p0[2] = cvt2(t1[0], t1[1]); p0[3] = cvt2(t1[2], t1[3]);
        p1[0] = cvt2(t2[0], t2[1]); p1[1] = cvt2(t2[2], t2[3]);
        p1[2] = cvt2(t3[0], t3[1]); p1[3] = cvt2(t3[2], t3[3]);
        *(bf16x8*)(&Al[r * 264 + cb]) = v0;
        *(bf16x8*)(&Al[r * 264 + cb + 8]) = v1;
    }
    __syncthreads();

    bf16x8 af[8];
#pragma unroll
    for (int ks = 0; ks < 8; ++ks)
        af[ks] = *(const bf16x8*)(&Al[col * 264 + ks * 32 + quad * 8]);

#pragma unroll
    for (int ctl = 0; ctl < 2; ++ctl) {
        f32x4 acc = {0.f, 0.f, 0.f, 0.f};
#pragma unroll
        for (int ks = 0; ks < 8; ++ks)
            acc = __builtin_amdgcn_mfma_f32_16x16x32_bf16(af[ks], bfr[ctl * 8 + ks], acc, 0, 0, 0);
        int c = colhalf * 128 + w * 32 + ctl * 16 + col;
        float s = 0.f, q = 0.f;
#pragma unroll
        for (int rr = 0; rr < 4; ++rr) {
            float v = acc[rr];
            tokpart[(size_t)(rowbase + quad * 4 + rr) * C_ + c] = v;
            s += v; q += v * v;
        }
        s += __shfl_xor(s, 16, 64); s += __shfl_xor(s, 32, 64);
        q += __shfl_xor(q, 16, 64); q += __shfl_xor(q, 32, 64);
        if (l < 16) {
            int cc = colhalf * 128 + w * 32 + ctl * 16 + l;
            atomicAdd(p1s + slot * C_ + cc, s);
            atomicAdd(p1q + slot * C_ + cc, q);
        }
    }
    if (colhalf == 0) {
        const f32x4* wcp = (const f32x4*)(Wc + l * 12);
        f32x4 wa = wcp[0], wb = wcp[1], wv = wcp[2];
        float wcl[12] = {wa[0], wa[1], wa[2], wa[3], wb[0], wb[1], wb[2], wb[3],
                         wv[0], wv[1], wv[2], wv[3]};
#pragma unroll
        for (int rr = 0; rr < 4; ++rr) {
            int r = w * 4 + rr;
            bf16x4 tv4 = *(const bf16x4*)(&Al[r * 264 + l * 4]);
            float p[3] = {0.f, 0.f, 0.f};
#pragma unroll
            for (int i = 0; i < 4; ++i) {
                float tvf = (float)tv4[i];
#pragma unroll
                for (int j = 0; j < 3; ++j) p[j] = fmaf(tvf, wcl[i * 3 + j], p[j]);
            }
#pragma unroll
            for (int off = 1; off < 64; off <<= 1)
#pragma unroll
                for (int j = 0; j < 3; ++j) p[j] += __shfl_xor(p[j], off, 64);
            if (l == 0) {
#pragma unroll
                for (int j = 0; j < 3; ++j)
                    coarse[(size_t)(rowbase + r) * 3 + j] = p[j] + bc[j];
            }
        }
    }
}

// ---------------- K1b: BN1 params + folded grid-weight vectors ----------------------
__global__ void k1b(const float* __restrict__ grid, const float* __restrict__ W1,
                    const float* __restrict__ gamma1, const float* __restrict__ beta1,
                    const float* __restrict__ p1s, const float* __restrict__ p1q,
                    float* __restrict__ a1o, float* __restrict__ d1o,
                    float* __restrict__ wgxo, float* __restrict__ wgyo) {
    int t = threadIdx.x;
    float S = 0.f, Qq = 0.f;
    for (int s = 0; s < 32; ++s) { S += p1s[s * C_ + t]; Qq += p1q[s * C_ + t]; }
    float mean_t = S / (float)ROWS;
    float var_t = Qq / (float)ROWS - mean_t * mean_t;
    float wx = W1[C_ * H1_ + t];
    float wy = W1[(C_ + 1) * H1_ + t];
    float mg = 0.f, qg = 0.f;
    for (int n = 0; n < 64; ++n) {
        float gv = grid[2 * n] * wx + grid[2 * n + 1] * wy;
        mg += gv; qg += gv * gv;
    }
    mg *= (1.f / 64.f);
    float var_g = qg * (1.f / 64.f) - mg * mg;
    float a1 = gamma1[t] * rsqrtf(var_t + var_g + EPSN);
    a1o[t] = a1;
    d1o[t] = beta1[t] - a1 * (mean_t + mg);
    wgxo[t] = a1 * wx;
    wgyo[t] = a1 * wy;
}

// ---------------- Kfold: tokfold = a1 * tokpart + d1 (memory-bound) -----------------
__global__ __launch_bounds__(256) void kfold(const float* __restrict__ tokpart,
                                             const float* __restrict__ a1,
                                             const float* __restrict__ d1,
                                             float* __restrict__ tokfold) {
    int idx = blockIdx.x * 256 + threadIdx.x;
    int c0 = (idx * 4) & 255;
    f32x4 a = *(const f32x4*)(a1 + c0);
    f32x4 d = *(const f32x4*)(d1 + c0);
    f32x4 v = *(const f32x4*)(tokpart + (size_t)idx * 4);
    *(f32x4*)(tokfold + (size_t)idx * 4) = __builtin_elementwise_fma(a, v, d);
}

// ---------------- K2x: exact BN2 stats, in-register A-frags, no LDS, no barriers ----
// Block (256 thr) = 8 rows x 32n-half x 64c2. Waves: (wn 0..1) x (wc 0..1).
__global__ __launch_bounds__(256) void k2x(const float* __restrict__ tokfold,
                                           const float* __restrict__ grid,
                                           const __bf16* __restrict__ W2p,
                                           const float* __restrict__ wgx,
                                           const float* __restrict__ wgy,
                                           float* __restrict__ p2s,
                                           float* __restrict__ p2q) {
    int t = threadIdx.x, w = t >> 6, l = t & 63;
    int quad = l >> 4, col = l & 15;
    int wn = w >> 1, wc = w & 1;
    int rowgrp = blockIdx.x >> 1, nh = blockIdx.x & 1;
    int n = nh * 32 + wn * 16 + col;
    float gx = grid[2 * n], gy = grid[2 * n + 1];

    bf16x8 bfr[16];
#pragma unroll
    for (int ck = 0; ck < 2; ++ck)
#pragma unroll
        for (int ks = 0; ks < 8; ++ks) {
            int CK = wc * 2 + ck;
            bfr[ck * 8 + ks] = *(const bf16x8*)(W2p + (((CK * 8 + ks) * 64 + l) * 8));
        }

    // per-lane grid term for its 64 channels: c = ks*32 + quad*8 + e
    f32x4 gt[16];
    f32x4 gx4 = {gx, gx, gx, gx}, gy4 = {gy, gy, gy, gy};
#pragma unroll
    for (int ks = 0; ks < 8; ++ks) {
        int cb = ks * 32 + quad * 8;
        f32x4 wx0 = *(const f32x4*)(wgx + cb), wx1 = *(const f32x4*)(wgx + cb + 4);
        f32x4 wy0 = *(const f32x4*)(wgy + cb), wy1 = *(const f32x4*)(wgy + cb + 4);
        gt[2 * ks]     = __builtin_elementwise_fma(gy4, wy0, gx4 * wx0);
        gt[2 * ks + 1] = __builtin_elementwise_fma(gy4, wy1, gx4 * wx1);
    }

    float s[8] = {}, q[8] = {};
    const f32x4 z4 = {0.f, 0.f, 0.f, 0.f};

#pragma unroll 1
    for (int r8 = 0; r8 < 8; ++r8) {
        const float* tr = tokfold + (size_t)(rowgrp * 8 + r8) * C_;
        bf16x8 af[8];
#pragma unroll
        for (int ks = 0; ks < 8; ++ks) {
            int cb = ks * 32 + quad * 8;
            f32x4 t0 = *(const f32x4*)(tr + cb);
            f32x4 t1 = *(const f32x4*)(tr + cb + 4);
            f32x4 v0 = __builtin_elementwise_max(t0 + gt[2 * ks], z4);
            f32x4 v1 = __builtin_elementwise_max(t1 + gt[2 * ks + 1], z4);
            bf16x2* o = (bf16x2*)&af[ks];
            o[0] = cvt2(v0[0], v0[1]); o[1] = cvt2(v0[2], v0[3]);
            o[2] = cvt2(v1[0], v1[1]); o[3] = cvt2(v1[2], v1[3]);
        }
#pragma unroll
        for (int ck = 0; ck < 2; ++ck) {
            f32x4 acc = {0.f, 0.f, 0.f, 0.f};
#pragma unroll
            for (int ks = 0; ks < 8; ++ks)
                acc = __builtin_amdgcn_mfma_f32_16x16x32_bf16(bfr[ck * 8 + ks], af[ks], acc, 0, 0, 0);
            // acc[rr] = h2pre[n = nh*32+wn*16+(l&15)][c2 = wc*32+ck*16+quad*4+rr]
#pragma unroll
            for (int rr = 0; rr < 4; ++rr) {
                s[ck * 4 + rr] += acc[rr];
                q[ck * 4 + rr] = fmaf(acc[rr], acc[rr], q[ck * 4 + rr]);
            }
        }
    }
    int slot = blockIdx.x & 63;
#pragma unroll
    for (int i = 0; i < 8; ++i) {
        float sv = s[i], qv = q[i];
        sv += __shfl_xor(sv, 1, 64); sv += __shfl_xor(sv, 2, 64);
        sv += __shfl_xor(sv, 4, 64); sv += __shfl_xor(sv, 8, 64);
        qv += __shfl_xor(qv, 1, 64); qv += __shfl_xor(qv, 2, 64);
        qv += __shfl_xor(qv, 4, 64); qv += __shfl_xor(qv, 8, 64);
        if (col == 0) {
            int c2 = wc * 32 + (i >> 2) * 16 + quad * 4 + (i & 3);
            atomicAdd(p2s + slot * H2_ + c2, sv);
            atomicAdd(p2q + slot * H2_ + c2, qv);
        }
    }
}

// ---------------- K2b: BN2 params (raw-acc stats; b2 cancels) -----------------------
__global__ void k2b(const float* __restrict__ p2s, const float* __restrict__ p2q,
                    const float* __restrict__ gamma2, const float* __restrict__ beta2,
                    float* __restrict__ a2o, float* __restrict__ d2o) {
    int t = threadIdx.x;
    float S = 0.f, Qq = 0.f;
    for (int s = 0; s < 64; ++s) { S += p2s[s * H2_ + t]; Qq += p2q[s * H2_ + t]; }
    const float invN = 1.f / ((float)ROWS * 64.f);
    float mean = S * invN;
    float var = Qq * invN - mean * mean;
    float a2 = gamma2[t] * rsqrtf(var + EPSN);
    a2o[t] = a2;
    d2o[t] = beta2[t] - a2 * mean;
}

// ---------------- K3x: output pass — same staging, BN2+ReLU, W3 MFMA tail -----------
__global__ __launch_bounds__(256) void k3x(const float* __restrict__ tokfold,
                                           const float* __restrict__ grid,
                                           const __bf16* __restrict__ W2p,
                                           const float* __restrict__ wgx,
                                           const float* __restrict__ wgy,
                                           const float* __restrict__ a2,
                                           const float* __restrict__ d2p,
                                           const __bf16* __restrict__ W3p,
                                           const float* __restrict__ b3,
                                           const float* __restrict__ coarse,
                                           float* __restrict__ fine) {
    __shared__ __align__(16) __bf16 y2l[8 * 32 * 72];   // 36,864 B
    __shared__ __align__(16) float finebuf[8 * 96];     //  3,072 B
    int t = threadIdx.x, w = t >> 6, l = t & 63;
    int quad = l >> 4, col = l & 15;
    int wn = w >> 1, wc = w & 1;
    int rowgrp = blockIdx.x >> 1, nh = blockIdx.x & 1;
    int n = nh * 32 + wn * 16 + col;
    float gx = grid[2 * n], gy = grid[2 * n + 1];

    bf16x8 bfr[16];
#pragma unroll
    for (int ck = 0; ck < 2; ++ck)
#pragma unroll
        for (int ks = 0; ks < 8; ++ks) {
            int CK = wc * 2 + ck;
            bfr[ck * 8 + ks] = *(const bf16x8*)(W2p + (((CK * 8 + ks) * 64 + l) * 8));
        }
    f32x4 gt[16];
    f32x4 gx4 = {gx, gx, gx, gx}, gy4 = {gy, gy, gy, gy};
#pragma unroll
    for (int ks = 0; ks < 8; ++ks) {
        int cb = ks * 32 + quad * 8;
        f32x4 wx0 = *(const f32x4*)(wgx + cb), wx1 = *(const f32x4*)(wgx + cb + 4);
        f32x4 wy0 = *(const f32x4*)(wgy + cb), wy1 = *(const f32x4*)(wgy + cb + 4);
        gt[2 * ks]     = __builtin_elementwise_fma(gy4, wy0, gx4 * wx0);
        gt[2 * ks + 1] = __builtin_elementwise_fma(gy4, wy1, gx4 * wx1);
    }
    float a2v[8], d2v[8];
#pragma unroll
    for (int ck = 0; ck < 2; ++ck)
#pragma unroll
        for (int rr = 0; rr < 4; ++rr) {
            int c2 = wc * 32 + ck * 16 + quad * 4 + rr;
            a2v[ck * 4 + rr] = a2[c2];
            d2v[ck * 4 + rr] = d2p[c2];
        }
    const f32x4 z4 = {0.f, 0.f, 0.f, 0.f};

#pragma unroll 1
    for (int r8 = 0; r8 < 8; ++r8) {
        const float* tr = tokfold + (size_t)(rowgrp * 8 + r8) * C_;
        bf16x8 af[8];
#pragma unroll
        for (int ks = 0; ks < 8; ++ks) {
            int cb = ks * 32 + quad * 8;
            f32x4 t0 = *(const f32x4*)(tr + cb);
            f32x4 t1 = *(const f32x4*)(tr + cb + 4);
            f32x4 v0 = __builtin_elementwise_max(t0 + gt[2 * ks], z4);
            f32x4 v1 = __builtin_elementwise_max(t1 + gt[2 * ks + 1], z4);
            bf16x2* o = (bf16x2*)&af[ks];
            o[0] = cvt2(v0[0], v0[1]); o[1] = cvt2(v0[2], v0[3]);
            o[2] = cvt2(v1[0], v1[1]); o[3] = cvt2(v1[2], v1[3]);
        }
#pragma unroll
        for (int ck = 0; ck < 2; ++ck) {
            f32x4 acc = {0.f, 0.f, 0.f, 0.f};
#pragma unroll
            for (int ks = 0; ks < 8; ++ks)
                acc = __builtin_amdgcn_mfma_f32_16x16x32_bf16(bfr[ck * 8 + ks], af[ks], acc, 0, 0, 0);
            bf16x4 v; bf16x2* v2 = (bf16x2*)&v;
            float y0 = fmaxf(fmaf(a2v[ck * 4 + 0], acc[0], d2v[ck * 4 + 0]), 0.f);
            float y1 = fmaxf(fmaf(a2v[ck * 4 + 1], acc[1], d2v[ck * 4 + 1]), 0.f);
            float y2 = fmaxf(fmaf(a2v[ck * 4 + 2], acc[2], d2v[ck * 4 + 2]), 0.f);
            float y3 = fmaxf(fmaf(a2v[ck * 4 + 3], acc[3], d2v[ck * 4 + 3]), 0.f);
            v2[0] = cvt2(y0, y1); v2[1] = cvt2(y2, y3);
            *(bf16x4*)(&y2l[r8 * 2304 + (wn * 16 + col) * 72 + wc * 32 + ck * 16 + quad * 4]) = v;
        }
    }
    __syncthreads();
    // W3 tail: 16 tile-tasks (8 rows x 2 n-tiles), 4 per wave
    bf16x8 wfr[2];
#pragma unroll
    for (int ks = 0; ks < 2; ++ks)
        wfr[ks] = *(const bf16x8*)(W3p + ((ks * 64 + l) * 8));
    float b3v = (col < 3) ? b3[col] : 0.f;
#pragma unroll
    for (int i = 0; i < 4; ++i) {
        int tt = w * 4 + i;
        int r8 = tt >> 1, nt = tt & 1;
        bf16x8 af2[2];
#pragma unroll
        for (int k2 = 0; k2 < 2; ++k2)
            af2[k2] = *(const bf16x8*)(&y2l[r8 * 2304 + (nt * 16 + col) * 72 + k2 * 32 + quad * 8]);
        f32x4 acc = {0.f, 0.f, 0.f, 0.f};
        acc = __builtin_amdgcn_mfma_f32_16x16x32_bf16(af2[0], wfr[0], acc, 0, 0, 0);
        acc = __builtin_amdgcn_mfma_f32_16x16x32_bf16(af2[1], wfr[1], acc, 0, 0, 0);
        if (col < 3) {
            int row = rowgrp * 8 + r8;
            float cj = coarse[row * 3 + col] + b3v;
#pragma unroll
            for (int rr = 0; rr < 4; ++rr)
                finebuf[r8 * 96 + (nt * 16 + quad * 4 + rr) * 3 + col] = acc[rr] + cj;
        }
    }
    __syncthreads();
    if (t < 192) {
        int r8 = t / 24, wi = t - r8 * 24;
        float* dst = fine + ((size_t)(rowgrp * 8 + r8) * 64 + nh * 32) * 3 + wi * 4;
        *(f32x4*)dst = ((const f32x4*)finebuf)[t];
    }
}

// ---------------- host launcher -----------------------------------------------------
extern "C" void kernel_launch(void* const* d_in, const int* in_sizes, int n_in,
                              void* d_out, int out_size, void* d_ws, size_t ws_size,
                              hipStream_t stream) {
    (void)in_sizes; (void)n_in; (void)out_size; (void)ws_size;
    const float* tokens = (const float*)d_in[0];
    const float* grid   = (const float*)d_in[1];
    const float* Wc     = (const float*)d_in[2];
    const float* bc     = (const float*)d_in[3];
    const float* W1     = (const float*)d_in[4];
    const float* gamma1 = (const float*)d_in[6];
    const float* beta1  = (const float*)d_in[7];
    const float* W2     = (const float*)d_in[8];
    const float* gamma2 = (const float*)d_in[10];
    const float* beta2  = (const float*)d_in[11];
    const float* W3     = (const float*)d_in[12];
    const float* b3     = (const float*)d_in[13];

    char* ws = (char*)d_ws;
    __bf16* W1p     = (__bf16*)(ws);                     // 131072 B
    __bf16* W2p     = (__bf16*)(ws + 131072);            //  32768 B
    float*  p1s     = (float*)(ws + 163840);             //  32768 B
    float*  p1q     = (float*)(ws + 196608);             //  32768 B
    float*  p2s     = (float*)(ws + 229376);             //  16384 B
    float*  p2q     = (float*)(ws + 245760);             //  16384 B
    float*  a1      = (float*)(ws + 262144);             //   1024 B
    float*  d1      = (float*)(ws + 263168);             //   1024 B
    float*  a2      = (float*)(ws + 264192);             //    256 B
    float*  d2p     = (float*)(ws + 264448);             //    256 B
    __bf16* W3p     = (__bf16*)(ws + 264704);            //   2048 B
    float*  wgx     = (float*)(ws + 266752);             //   1024 B
    float*  wgy     = (float*)(ws + 267776);             //   1024 B
    float*  tokpart = (float*)(ws + 268800);             // 16777216 B
    float*  tokfold = (float*)(ws + 17046016);           // 16777216 B

    float* coarse = (float*)d_out;
    float* fine   = (float*)d_out + (size_t)ROWS * 3;

    k0_pack<<<320, 256, 0, stream>>>(W1, W2, W3, W1p, W2p, W3p, p1s);
    k1a<<<2048, 256, 0, stream>>>(tokens, W1p, Wc, bc, tokpart, coarse, p1s, p1q);
    k1b<<<1, 256, 0, stream>>>(grid, W1, gamma1, beta1, p1s, p1q, a1, d1, wgx, wgy);
    kfold<<<4096, 256, 0, stream>>>(tokpart, a1, d1, tokfold);
    k2x<<<4096, 256, 0, stream>>>(tokfold, grid, W2p, wgx, wgy, p2s, p2q);
    k2b<<<1, 64, 0, stream>>>(p2s, p2q, gamma2, beta2, a2, d2p);
    k3x<<<4096, 256, 0, stream>>>(tokfold, grid, W2p, wgx, wgy, a2, d2p, W3p, b3, coarse, fine);
}

// Round 7
// 251.617 us; speedup vs baseline: 1.2490x; 1.2490x over previous
//
#include <hip/hip_runtime.h>
#include <hip/hip_bf16.h>

#define ROWS 16384
#define C_   256
#define H1_  256
#define H2_  64
#define EPSN 1e-5f

typedef __bf16 bf16x8 __attribute__((ext_vector_type(8)));
typedef __bf16 bf16x4 __attribute__((ext_vector_type(4)));
typedef __bf16 bf16x2 __attribute__((ext_vector_type(2)));
typedef float  f32x4  __attribute__((ext_vector_type(4)));
typedef float  f32x2  __attribute__((ext_vector_type(2)));

__device__ __forceinline__ bf16x2 cvt2(float a, float b) {
#if __has_builtin(__builtin_amdgcn_cvt_pk_bf16_f32)
    return __builtin_bit_cast(bf16x2, __builtin_amdgcn_cvt_pk_bf16_f32(a, b));
#else
    bf16x2 r; r[0] = (__bf16)a; r[1] = (__bf16)b; return r;
#endif
}

// ---------------- K0: pack W1/W2/W3 into MFMA fragment order, zero partial buffers --
__global__ __launch_bounds__(256) void k0_pack(const float* __restrict__ W1,
                                               const float* __restrict__ W2,
                                               const float* __restrict__ W3,
                                               __bf16* __restrict__ W1p,
                                               __bf16* __restrict__ W2p,
                                               __bf16* __restrict__ W3p,
                                               float* __restrict__ zero_base) {
    int idx = blockIdx.x * 256 + threadIdx.x;   // 0 .. 81919
    if (idx < 65536) {
        int j = idx & 7, l = (idx >> 3) & 63, rest = idx >> 9;
        int ks = rest & 7, CT = rest >> 3;
        int k = ks * 32 + ((l >> 4) << 3) + j;
        int c = CT * 16 + (l & 15);
        W1p[idx] = (__bf16)W1[k * H1_ + c];
    } else {
        int i2 = idx - 65536;
        int j = i2 & 7, l = (i2 >> 3) & 63, rest = i2 >> 9;
        int ks = rest & 7, CK = rest >> 3;
        int k = ks * 32 + ((l >> 4) << 3) + j;
        int c2 = CK * 16 + (l & 15);
        W2p[i2] = (__bf16)W2[k * H2_ + c2];
    }
    if (idx < 1024) {
        int j = idx & 7, l = (idx >> 3) & 63, ks = idx >> 9;
        int k = ks * 32 + ((l >> 4) << 3) + j;
        int c = l & 15;
        W3p[idx] = (c < 3) ? (__bf16)W3[k * 3 + c] : (__bf16)0.f;
    }
    if (idx < 24576) zero_base[idx] = 0.0f;     // p1s,p1q,p2s,p2q contiguous
}

// ---------------- K1a: tokpart = tokens @ W1[:C] ; per-channel stats ; coarse -------
__global__ __launch_bounds__(256) void k1a(const float* __restrict__ tokens,
                                           const __bf16* __restrict__ W1p,
                                           const float* __restrict__ Wc,
                                           const float* __restrict__ bc,
                                           float* __restrict__ tokpart,
                                           float* __restrict__ coarse,
                                           float* __restrict__ p1s,
                                           float* __restrict__ p1q) {
    __shared__ __align__(16) __bf16 Al[16 * 264];
    int t = threadIdx.x, w = t >> 6, l = t & 63;
    int quad = l >> 4, col = l & 15;
    int rowbase = (blockIdx.x >> 1) * 16;
    int colhalf = blockIdx.x & 1;
    int slot = blockIdx.x & 31;

    bf16x8 bfr[16];
#pragma unroll
    for (int ctl = 0; ctl < 2; ++ctl)
#pragma unroll
        for (int ks = 0; ks < 8; ++ks) {
            int CT = colhalf * 8 + w * 2 + ctl;
            bfr[ctl * 8 + ks] = *(const bf16x8*)(W1p + (((CT * 8 + ks) * 64 + l) * 8));
        }
    {
        int r = t >> 4, cb = (t & 15) * 16;
        const float* src = tokens + (size_t)(rowbase + r) * C_ + cb;
        f32x4 t0 = *(const f32x4*)(src);
        f32x4 t1 = *(const f32x4*)(src + 4);
        f32x4 t2 = *(const f32x4*)(src + 8);
        f32x4 t3 = *(const f32x4*)(src + 12);
        bf16x8 v0, v1;
        bf16x2* p0 = (bf16x2*)&v0; bf16x2* p1 = (bf16x2*)&v1;
        p0[0] = cvt2(t0[0], t0[1]); p0[1] = cvt2(t0[2], t0[3]);
        p0[2] = cvt2(t1[0], t1[1]); p0[3] = cvt2(t1[2], t1[3]);
        p1[0] = cvt2(t2[0], t2[1]); p1[1] = cvt2(t2[2], t2[3]);
        p1[2] = cvt2(t3[0], t3[1]); p1[3] = cvt2(t3[2], t3[3]);
        *(bf16x8*)(&Al[r * 264 + cb]) = v0;
        *(bf16x8*)(&Al[r * 264 + cb + 8]) = v1;
    }
    __syncthreads();

    bf16x8 af[8];
#pragma unroll
    for (int ks = 0; ks < 8; ++ks)
        af[ks] = *(const bf16x8*)(&Al[col * 264 + ks * 32 + quad * 8]);

#pragma unroll
    for (int ctl = 0; ctl < 2; ++ctl) {
        f32x4 acc = {0.f, 0.f, 0.f, 0.f};
#pragma unroll
        for (int ks = 0; ks < 8; ++ks)
            acc = __builtin_amdgcn_mfma_f32_16x16x32_bf16(af[ks], bfr[ctl * 8 + ks], acc, 0, 0, 0);
        int c = colhalf * 128 + w * 32 + ctl * 16 + col;
        float s = 0.f, q = 0.f;
#pragma unroll
        for (int rr = 0; rr < 4; ++rr) {
            float v = acc[rr];
            tokpart[(size_t)(rowbase + quad * 4 + rr) * C_ + c] = v;
            s += v; q += v * v;
        }
        s += __shfl_xor(s, 16, 64); s += __shfl_xor(s, 32, 64);
        q += __shfl_xor(q, 16, 64); q += __shfl_xor(q, 32, 64);
        if (l < 16) {
            int cc = colhalf * 128 + w * 32 + ctl * 16 + l;
            atomicAdd(p1s + slot * C_ + cc, s);
            atomicAdd(p1q + slot * C_ + cc, q);
        }
    }
    if (colhalf == 0) {
        const f32x4* wcp = (const f32x4*)(Wc + l * 12);
        f32x4 wa = wcp[0], wb = wcp[1], wv = wcp[2];
        float wcl[12] = {wa[0], wa[1], wa[2], wa[3], wb[0], wb[1], wb[2], wb[3],
                         wv[0], wv[1], wv[2], wv[3]};
#pragma unroll
        for (int rr = 0; rr < 4; ++rr) {
            int r = w * 4 + rr;
            bf16x4 tv4 = *(const bf16x4*)(&Al[r * 264 + l * 4]);
            float p[3] = {0.f, 0.f, 0.f};
#pragma unroll
            for (int i = 0; i < 4; ++i) {
                float tvf = (float)tv4[i];
#pragma unroll
                for (int j = 0; j < 3; ++j) p[j] = fmaf(tvf, wcl[i * 3 + j], p[j]);
            }
#pragma unroll
            for (int off = 1; off < 64; off <<= 1)
#pragma unroll
                for (int j = 0; j < 3; ++j) p[j] += __shfl_xor(p[j], off, 64);
            if (l == 0) {
#pragma unroll
                for (int j = 0; j < 3; ++j)
                    coarse[(size_t)(rowbase + r) * 3 + j] = p[j] + bc[j];
            }
        }
    }
}

// ---------------- K1b: BN1 params + folded grid-weight vectors ----------------------
__global__ void k1b(const float* __restrict__ grid, const float* __restrict__ W1,
                    const float* __restrict__ gamma1, const float* __restrict__ beta1,
                    const float* __restrict__ p1s, const float* __restrict__ p1q,
                    float* __restrict__ a1o, float* __restrict__ d1o,
                    float* __restrict__ wgxo, float* __restrict__ wgyo) {
    int t = threadIdx.x;
    float S = 0.f, Qq = 0.f;
    for (int s = 0; s < 32; ++s) { S += p1s[s * C_ + t]; Qq += p1q[s * C_ + t]; }
    float mean_t = S / (float)ROWS;
    float var_t = Qq / (float)ROWS - mean_t * mean_t;
    float wx = W1[C_ * H1_ + t];
    float wy = W1[(C_ + 1) * H1_ + t];
    float mg = 0.f, qg = 0.f;
    for (int n = 0; n < 64; ++n) {
        float gv = grid[2 * n] * wx + grid[2 * n + 1] * wy;
        mg += gv; qg += gv * gv;
    }
    mg *= (1.f / 64.f);
    float var_g = qg * (1.f / 64.f) - mg * mg;
    float a1 = gamma1[t] * rsqrtf(var_t + var_g + EPSN);
    a1o[t] = a1;
    d1o[t] = beta1[t] - a1 * (mean_t + mg);
    wgxo[t] = a1 * wx;
    wgyo[t] = a1 * wy;
}

// ---------------- K2x: BN2 stats. LDS row-broadcast + in-register A-frags -----------
// Block (256 thr) = 8 rows x 32n-half x 64c2. Waves: (wn 0..1) x (wc 0..1).
// rowbuf = a1*tokpart + d1, staged once per block; row loop is barrier-free.
__global__ __launch_bounds__(256) void k2x(const float* __restrict__ tokpart,
                                           const float* __restrict__ grid,
                                           const __bf16* __restrict__ W2p,
                                           const float* __restrict__ wgx,
                                           const float* __restrict__ wgy,
                                           const float* __restrict__ a1,
                                           const float* __restrict__ d1,
                                           float* __restrict__ p2s,
                                           float* __restrict__ p2q) {
    __shared__ __align__(16) float rowbuf[8 * 256];     // 8 KB
    int t = threadIdx.x, w = t >> 6, l = t & 63;
    int quad = l >> 4, col = l & 15;
    int wn = w >> 1, wc = w & 1;
    int rowgrp = blockIdx.x >> 1, nh = blockIdx.x & 1;
    int n = nh * 32 + wn * 16 + col;
    float gx = grid[2 * n], gy = grid[2 * n + 1];

    bf16x8 bfr[16];
#pragma unroll
    for (int ck = 0; ck < 2; ++ck)
#pragma unroll
        for (int ks = 0; ks < 8; ++ks) {
            int CK = wc * 2 + ck;
            bfr[ck * 8 + ks] = *(const bf16x8*)(W2p + (((CK * 8 + ks) * 64 + l) * 8));
        }

    // stage 8 rows, pre-folded with a1/d1 (coalesced; channel set constant per thread)
    {
        int ch4 = (4 * t) & 255;
        f32x4 a4 = *(const f32x4*)(a1 + ch4);
        f32x4 d4 = *(const f32x4*)(d1 + ch4);
        const float* src = tokpart + (size_t)rowgrp * (8 * C_);
#pragma unroll
        for (int i = 0; i < 2; ++i) {
            int idx = 4 * t + 1024 * i;
            f32x4 v = *(const f32x4*)(src + idx);
            *(f32x4*)(&rowbuf[idx]) = __builtin_elementwise_fma(a4, v, d4);
        }
    }

    // per-lane grid term for its 64 channels: c = ks*32 + quad*8 + e
    f32x4 gt[16];
    f32x4 gx4 = {gx, gx, gx, gx}, gy4 = {gy, gy, gy, gy};
#pragma unroll
    for (int ks = 0; ks < 8; ++ks) {
        int cb = ks * 32 + quad * 8;
        f32x4 wx0 = *(const f32x4*)(wgx + cb), wx1 = *(const f32x4*)(wgx + cb + 4);
        f32x4 wy0 = *(const f32x4*)(wgy + cb), wy1 = *(const f32x4*)(wgy + cb + 4);
        gt[2 * ks]     = __builtin_elementwise_fma(gy4, wy0, gx4 * wx0);
        gt[2 * ks + 1] = __builtin_elementwise_fma(gy4, wy1, gx4 * wx1);
    }
    __syncthreads();

    float s[8] = {}, q[8] = {};
    const f32x4 z4 = {0.f, 0.f, 0.f, 0.f};

#pragma unroll 1
    for (int r8 = 0; r8 < 8; ++r8) {
        const float* tr = &rowbuf[r8 * 256];
        bf16x8 af[8];
#pragma unroll
        for (int ks = 0; ks < 8; ++ks) {
            int cb = ks * 32 + quad * 8;
            f32x4 t0 = *(const f32x4*)(tr + cb);
            f32x4 t1 = *(const f32x4*)(tr + cb + 4);
            f32x4 v0 = __builtin_elementwise_max(t0 + gt[2 * ks], z4);
            f32x4 v1 = __builtin_elementwise_max(t1 + gt[2 * ks + 1], z4);
            bf16x2* o = (bf16x2*)&af[ks];
            o[0] = cvt2(v0[0], v0[1]); o[1] = cvt2(v0[2], v0[3]);
            o[2] = cvt2(v1[0], v1[1]); o[3] = cvt2(v1[2], v1[3]);
        }
#pragma unroll
        for (int ck = 0; ck < 2; ++ck) {
            f32x4 acc = {0.f, 0.f, 0.f, 0.f};
#pragma unroll
            for (int ks = 0; ks < 8; ++ks)
                acc = __builtin_amdgcn_mfma_f32_16x16x32_bf16(bfr[ck * 8 + ks], af[ks], acc, 0, 0, 0);
            // acc[rr] = h2pre[n][c2 = wc*32+ck*16+quad*4+rr]
#pragma unroll
            for (int rr = 0; rr < 4; ++rr) {
                s[ck * 4 + rr] += acc[rr];
                q[ck * 4 + rr] = fmaf(acc[rr], acc[rr], q[ck * 4 + rr]);
            }
        }
    }
    int slot = blockIdx.x & 63;
#pragma unroll
    for (int i = 0; i < 8; ++i) {
        float sv = s[i], qv = q[i];
        sv += __shfl_xor(sv, 1, 64); sv += __shfl_xor(sv, 2, 64);
        sv += __shfl_xor(sv, 4, 64); sv += __shfl_xor(sv, 8, 64);
        qv += __shfl_xor(qv, 1, 64); qv += __shfl_xor(qv, 2, 64);
        qv += __shfl_xor(qv, 4, 64); qv += __shfl_xor(qv, 8, 64);
        if (col == 0) {
            int c2 = wc * 32 + (i >> 2) * 16 + quad * 4 + (i & 3);
            atomicAdd(p2s + slot * H2_ + c2, sv);
            atomicAdd(p2q + slot * H2_ + c2, qv);
        }
    }
}

// ---------------- K2b: BN2 params (raw-acc stats; b2 cancels) -----------------------
__global__ void k2b(const float* __restrict__ p2s, const float* __restrict__ p2q,
                    const float* __restrict__ gamma2, const float* __restrict__ beta2,
                    float* __restrict__ a2o, float* __restrict__ d2o) {
    int t = threadIdx.x;
    float S = 0.f, Qq = 0.f;
    for (int s = 0; s < 64; ++s) { S += p2s[s * H2_ + t]; Qq += p2q[s * H2_ + t]; }
    const float invN = 1.f / ((float)ROWS * 64.f);
    float mean = S * invN;
    float var = Qq * invN - mean * mean;
    float a2 = gamma2[t] * rsqrtf(var + EPSN);
    a2o[t] = a2;
    d2o[t] = beta2[t] - a2 * mean;
}

// ---------------- K3x: output pass — same staging, BN2+ReLU, W3 MFMA tail -----------
__global__ __launch_bounds__(256) void k3x(const float* __restrict__ tokpart,
                                           const float* __restrict__ grid,
                                           const __bf16* __restrict__ W2p,
                                           const float* __restrict__ wgx,
                                           const float* __restrict__ wgy,
                                           const float* __restrict__ a1,
                                           const float* __restrict__ d1,
                                           const float* __restrict__ a2,
                                           const float* __restrict__ d2p,
                                           const __bf16* __restrict__ W3p,
                                           const float* __restrict__ b3,
                                           const float* __restrict__ coarse,
                                           float* __restrict__ fine) {
    __shared__ __align__(16) float rowbuf[8 * 256];     //  8,192 B
    __shared__ __align__(16) __bf16 y2l[8 * 32 * 72];   // 36,864 B
    __shared__ __align__(16) float finebuf[8 * 96];     //  3,072 B
    int t = threadIdx.x, w = t >> 6, l = t & 63;
    int quad = l >> 4, col = l & 15;
    int wn = w >> 1, wc = w & 1;
    int rowgrp = blockIdx.x >> 1, nh = blockIdx.x & 1;
    int n = nh * 32 + wn * 16 + col;
    float gx = grid[2 * n], gy = grid[2 * n + 1];

    bf16x8 bfr[16];
#pragma unroll
    for (int ck = 0; ck < 2; ++ck)
#pragma unroll
        for (int ks = 0; ks < 8; ++ks) {
            int CK = wc * 2 + ck;
            bfr[ck * 8 + ks] = *(const bf16x8*)(W2p + (((CK * 8 + ks) * 64 + l) * 8));
        }
    {
        int ch4 = (4 * t) & 255;
        f32x4 a4 = *(const f32x4*)(a1 + ch4);
        f32x4 d4 = *(const f32x4*)(d1 + ch4);
        const float* src = tokpart + (size_t)rowgrp * (8 * C_);
#pragma unroll
        for (int i = 0; i < 2; ++i) {
            int idx = 4 * t + 1024 * i;
            f32x4 v = *(const f32x4*)(src + idx);
            *(f32x4*)(&rowbuf[idx]) = __builtin_elementwise_fma(a4, v, d4);
        }
    }
    f32x4 gt[16];
    f32x4 gx4 = {gx, gx, gx, gx}, gy4 = {gy, gy, gy, gy};
#pragma unroll
    for (int ks = 0; ks < 8; ++ks) {
        int cb = ks * 32 + quad * 8;
        f32x4 wx0 = *(const f32x4*)(wgx + cb), wx1 = *(const f32x4*)(wgx + cb + 4);
        f32x4 wy0 = *(const f32x4*)(wgy + cb), wy1 = *(const f32x4*)(wgy + cb + 4);
        gt[2 * ks]     = __builtin_elementwise_fma(gy4, wy0, gx4 * wx0);
        gt[2 * ks + 1] = __builtin_elementwise_fma(gy4, wy1, gx4 * wx1);
    }
    float a2v[8], d2v[8];
#pragma unroll
    for (int ck = 0; ck < 2; ++ck)
#pragma unroll
        for (int rr = 0; rr < 4; ++rr) {
            int c2 = wc * 32 + ck * 16 + quad * 4 + rr;
            a2v[ck * 4 + rr] = a2[c2];
            d2v[ck * 4 + rr] = d2p[c2];
        }
    __syncthreads();

    const f32x4 z4 = {0.f, 0.f, 0.f, 0.f};
#pragma unroll 1
    for (int r8 = 0; r8 < 8; ++r8) {
        const float* tr = &rowbuf[r8 * 256];
        bf16x8 af[8];
#pragma unroll
        for (int ks = 0; ks < 8; ++ks) {
            int cb = ks * 32 + quad * 8;
            f32x4 t0 = *(const f32x4*)(tr + cb);
            f32x4 t1 = *(const f32x4*)(tr + cb + 4);
            f32x4 v0 = __builtin_elementwise_max(t0 + gt[2 * ks], z4);
            f32x4 v1 = __builtin_elementwise_max(t1 + gt[2 * ks + 1], z4);
            bf16x2* o = (bf16x2*)&af[ks];
            o[0] = cvt2(v0[0], v0[1]); o[1] = cvt2(v0[2], v0[3]);
            o[2] = cvt2(v1[0], v1[1]); o[3] = cvt2(v1[2], v1[3]);
        }
#pragma unroll
        for (int ck = 0; ck < 2; ++ck) {
            f32x4 acc = {0.f, 0.f, 0.f, 0.f};
#pragma unroll
            for (int ks = 0; ks < 8; ++ks)
                acc = __builtin_amdgcn_mfma_f32_16x16x32_bf16(bfr[ck * 8 + ks], af[ks], acc, 0, 0, 0);
            bf16x4 v; bf16x2* v2 = (bf16x2*)&v;
            float y0 = fmaxf(fmaf(a2v[ck * 4 + 0], acc[0], d2v[ck * 4 + 0]), 0.f);
            float y1 = fmaxf(fmaf(a2v[ck * 4 + 1], acc[1], d2v[ck * 4 + 1]), 0.f);
            float y2 = fmaxf(fmaf(a2v[ck * 4 + 2], acc[2], d2v[ck * 4 + 2]), 0.f);
            float y3 = fmaxf(fmaf(a2v[ck * 4 + 3], acc[3], d2v[ck * 4 + 3]), 0.f);
            v2[0] = cvt2(y0, y1); v2[1] = cvt2(y2, y3);
            *(bf16x4*)(&y2l[r8 * 2304 + (wn * 16 + col) * 72 + wc * 32 + ck * 16 + quad * 4]) = v;
        }
    }
    __syncthreads();
    // W3 tail: 16 tile-tasks (8 rows x 2 n-tiles), 4 per wave
    bf16x8 wfr[2];
#pragma unroll
    for (int ks = 0; ks < 2; ++ks)
        wfr[ks] = *(const bf16x8*)(W3p + ((ks * 64 + l) * 8));
    float b3v = (col < 3) ? b3[col] : 0.f;
#pragma unroll
    for (int i = 0; i < 4; ++i) {
        int tt = w * 4 + i;
        int r8 = tt >> 1, nt = tt & 1;
        bf16x8 af2[2];
#pragma unroll
        for (int k2 = 0; k2 < 2; ++k2)
            af2[k2] = *(const bf16x8*)(&y2l[r8 * 2304 + (nt * 16 + col) * 72 + k2 * 32 + quad * 8]);
        f32x4 acc = {0.f, 0.f, 0.f, 0.f};
        acc = __builtin_amdgcn_mfma_f32_16x16x32_bf16(af2[0], wfr[0], acc, 0, 0, 0);
        acc = __builtin_amdgcn_mfma_f32_16x16x32_bf16(af2[1], wfr[1], acc, 0, 0, 0);
        if (col < 3) {
            int row = rowgrp * 8 + r8;
            float cj = coarse[row * 3 + col] + b3v;
#pragma unroll
            for (int rr = 0; rr < 4; ++rr)
                finebuf[r8 * 96 + (nt * 16 + quad * 4 + rr) * 3 + col] = acc[rr] + cj;
        }
    }
    __syncthreads();
    if (t < 192) {
        int r8 = t / 24, wi = t - r8 * 24;
        float* dst = fine + ((size_t)(rowgrp * 8 + r8) * 64 + nh * 32) * 3 + wi * 4;
        *(f32x4*)dst = ((const f32x4*)finebuf)[t];
    }
}

// ---------------- host launcher -----------------------------------------------------
extern "C" void kernel_launch(void* const* d_in, const int* in_sizes, int n_in,
                              void* d_out, int out_size, void* d_ws, size_t ws_size,
                              hipStream_t stream) {
    (void)in_sizes; (void)n_in; (void)out_size; (void)ws_size;
    const float* tokens = (const float*)d_in[0];
    const float* grid   = (const float*)d_in[1];
    const float* Wc     = (const float*)d_in[2];
    const float* bc     = (const float*)d_in[3];
    const float* W1     = (const float*)d_in[4];
    const float* gamma1 = (const float*)d_in[6];
    const float* beta1  = (const float*)d_in[7];
    const float* W2     = (const float*)d_in[8];
    const float* gamma2 = (const float*)d_in[10];
    const float* beta2  = (const float*)d_in[11];
    const float* W3     = (const float*)d_in[12];
    const float* b3     = (const float*)d_in[13];

    char* ws = (char*)d_ws;
    __bf16* W1p     = (__bf16*)(ws);                     // 131072 B
    __bf16* W2p     = (__bf16*)(ws + 131072);            //  32768 B
    float*  p1s     = (float*)(ws + 163840);             //  32768 B
    float*  p1q     = (float*)(ws + 196608);             //  32768 B
    float*  p2s     = (float*)(ws + 229376);             //  16384 B
    float*  p2q     = (float*)(ws + 245760);             //  16384 B
    float*  a1      = (float*)(ws + 262144);             //   1024 B
    float*  d1      = (float*)(ws + 263168);             //   1024 B
    float*  a2      = (float*)(ws + 264192);             //    256 B
    float*  d2p     = (float*)(ws + 264448);             //    256 B
    __bf16* W3p     = (__bf16*)(ws + 264704);            //   2048 B
    float*  wgx     = (float*)(ws + 266752);             //   1024 B
    float*  wgy     = (float*)(ws + 267776);             //   1024 B
    float*  tokpart = (float*)(ws + 268800);             // 16777216 B

    float* coarse = (float*)d_out;
    float* fine   = (float*)d_out + (size_t)ROWS * 3;

    k0_pack<<<320, 256, 0, stream>>>(W1, W2, W3, W1p, W2p, W3p, p1s);
    k1a<<<2048, 256, 0, stream>>>(tokens, W1p, Wc, bc, tokpart, coarse, p1s, p1q);
    k1b<<<1, 256, 0, stream>>>(grid, W1, gamma1, beta1, p1s, p1q, a1, d1, wgx, wgy);
    k2x<<<4096, 256, 0, stream>>>(tokpart, grid, W2p, wgx, wgy, a1, d1, p2s, p2q);
    k2b<<<1, 64, 0, stream>>>(p2s, p2q, gamma2, beta2, a2, d2p);
    k3x<<<4096, 256, 0, stream>>>(tokpart, grid, W2p, wgx, wgy, a1, d1, a2, d2p, W3p, b3,
                                  coarse, fine);
}